// Round 1
// baseline (1909.949 us; speedup 1.0000x reference)
//
#include <hip/hip_runtime.h>

// Problem constants (from reference)
constexpr int cN0 = 819200, cN1 = 81920, cN2 = 8192;
constexpr int cE1 = 819200, cE2 = 81920;
constexpr int cDIN = 128, cDH = 256, cDOUT = 128;

// ---------------------------------------------------------------------------
// Scatter-add of source rows into destination accumulator (float atomics).
// D = feature dim (multiple of 4). One thread handles one float4 of one edge.
// ---------------------------------------------------------------------------
template<int D>
__global__ __launch_bounds__(256) void scatter_add_k(
    const float* __restrict__ xsrc, const int* __restrict__ src,
    const int* __restrict__ dst, float* __restrict__ agg, int nedges)
{
    constexpr int Q = D / 4;
    int gid = blockIdx.x * 256 + threadIdx.x;
    int e = gid / Q;
    int q = gid & (Q - 1);
    if (e >= nedges) return;
    int s = src[e];
    int d = dst[e];
    const float4 v = reinterpret_cast<const float4*>(xsrc)[(long)s * Q + q];
    float* o = agg + (long)d * D + q * 4;
    atomicAdd(o + 0, v.x);
    atomicAdd(o + 1, v.y);
    atomicAdd(o + 2, v.z);
    atomicAdd(o + 3, v.w);
}

__global__ __launch_bounds__(256) void count_k(
    const int* __restrict__ dst, float* __restrict__ cnt, int nedges)
{
    int e = blockIdx.x * 256 + threadIdx.x;
    if (e < nedges) atomicAdd(&cnt[dst[e]], 1.0f);
}

// ---------------------------------------------------------------------------
// Fused SAGE GEMM:  out = act( (agg/max(cnt,1)) @ W1 + xd @ W2 + bias )
//   agg, xd : [M][K1] row-major, W1,W2 : [K1][N] row-major.
// Tile 64x64, 256 threads, 4x4 micro-tile, BK=16, two K passes (agg, xd).
// M, N, K1 all multiples of 64/64/16 here -> no edge guards.
// ---------------------------------------------------------------------------
template<int K1, bool RELU>
__global__ __launch_bounds__(256) void sage_gemm_k(
    const float* __restrict__ agg, const float* __restrict__ cnt,
    const float* __restrict__ xd,
    const float* __restrict__ W1, const float* __restrict__ W2,
    const float* __restrict__ bias, float* __restrict__ out, int N)
{
    __shared__ float As[16][68];   // [k][row], padded stride 68 (16B-aligned rows)
    __shared__ float Ws[16][64];   // [k][col]

    const int tid = threadIdx.x;
    const int row0 = blockIdx.y * 64;
    const int n0 = blockIdx.x * 64;

    // loader indices
    const int lr = tid >> 2;          // 0..63  (A row within tile)
    const int lc = (tid & 3) * 4;     // 0,4,8,12 (A k-offset within chunk)
    const int wk = tid >> 4;          // 0..15 (W k-row within chunk)
    const int wc = (tid & 15) * 4;    // 0..60 (W col)
    // compute indices
    const int tr = (tid >> 4) * 4;    // 0..60 acc row base
    const int tc = (tid & 15) * 4;    // 0..60 acc col base

    float acc[4][4] = {};
    const float invc = 1.0f / fmaxf(cnt[row0 + lr], 1.0f);

    for (int pass = 0; pass < 2; ++pass) {
        const float* __restrict__ A = pass ? xd : agg;
        const float* __restrict__ W = pass ? W2 : W1;
        const float sc = pass ? 1.0f : invc;
        for (int k0 = 0; k0 < K1; k0 += 16) {
            float4 av = *reinterpret_cast<const float4*>(&A[(long)(row0 + lr) * K1 + k0 + lc]);
            float4 wv = *reinterpret_cast<const float4*>(&W[(long)(k0 + wk) * N + n0 + wc]);
            __syncthreads();   // previous chunk's reads done before overwrite
            As[lc + 0][lr] = av.x * sc;
            As[lc + 1][lr] = av.y * sc;
            As[lc + 2][lr] = av.z * sc;
            As[lc + 3][lr] = av.w * sc;
            *reinterpret_cast<float4*>(&Ws[wk][wc]) = wv;
            __syncthreads();
            #pragma unroll
            for (int kk = 0; kk < 16; ++kk) {
                float4 a = *reinterpret_cast<const float4*>(&As[kk][tr]);
                float4 b = *reinterpret_cast<const float4*>(&Ws[kk][tc]);
                acc[0][0] += a.x * b.x; acc[0][1] += a.x * b.y;
                acc[0][2] += a.x * b.z; acc[0][3] += a.x * b.w;
                acc[1][0] += a.y * b.x; acc[1][1] += a.y * b.y;
                acc[1][2] += a.y * b.z; acc[1][3] += a.y * b.w;
                acc[2][0] += a.z * b.x; acc[2][1] += a.z * b.y;
                acc[2][2] += a.z * b.z; acc[2][3] += a.z * b.w;
                acc[3][0] += a.w * b.x; acc[3][1] += a.w * b.y;
                acc[3][2] += a.w * b.z; acc[3][3] += a.w * b.w;
            }
        }
    }

    const float4 bv = *reinterpret_cast<const float4*>(&bias[n0 + tc]);
    #pragma unroll
    for (int i = 0; i < 4; ++i) {
        float4 o;
        o.x = acc[i][0] + bv.x;
        o.y = acc[i][1] + bv.y;
        o.z = acc[i][2] + bv.z;
        o.w = acc[i][3] + bv.w;
        if (RELU) {
            o.x = fmaxf(o.x, 0.0f); o.y = fmaxf(o.y, 0.0f);
            o.z = fmaxf(o.z, 0.0f); o.w = fmaxf(o.w, 0.0f);
        }
        *reinterpret_cast<float4*>(&out[(long)(row0 + tr + i) * N + n0 + tc]) = o;
    }
}

// ---------------------------------------------------------------------------
extern "C" void kernel_launch(void* const* d_in, const int* in_sizes, int n_in,
                              void* d_out, int out_size, void* d_ws, size_t ws_size,
                              hipStream_t stream)
{
    const float* x    = (const float*)d_in[0];
    const int*   src1 = (const int*)d_in[1];
    const int*   dst1 = (const int*)d_in[2];
    const int*   src2 = (const int*)d_in[3];
    const int*   dst2 = (const int*)d_in[4];
    // d_in[5]=n1, d_in[6]=n2 scalars (hard-coded constants)
    const float* w1l  = (const float*)d_in[7];
    const float* b1   = (const float*)d_in[8];
    const float* w1r  = (const float*)d_in[9];
    const float* w2l  = (const float*)d_in[10];
    const float* b2   = (const float*)d_in[11];
    const float* w2r  = (const float*)d_in[12];
    float* out = (float*)d_out;

    // workspace layout (fp32): agg1 | cnt1 | h | agg2 | cnt2  (~128.4 MB)
    float* agg1 = (float*)d_ws;
    float* cnt1 = agg1 + (size_t)cN1 * cDIN;
    float* h    = cnt1 + cN1;
    float* agg2 = h + (size_t)cN1 * cDH;
    float* cnt2 = agg2 + (size_t)cN2 * cDH;

    // zero accumulators every call (ws is poisoned once, never re-poisoned)
    hipMemsetAsync(agg1, 0, ((size_t)cN1 * cDIN + cN1) * sizeof(float), stream);
    hipMemsetAsync(agg2, 0, ((size_t)cN2 * cDH + cN2) * sizeof(float), stream);

    // ---- layer 1 aggregate: agg1[dst1] += x[src1], cnt1[dst1] += 1
    {
        int total = cE1 * (cDIN / 4);                 // 26,214,400 threads
        scatter_add_k<cDIN><<<total / 256, 256, 0, stream>>>(x, src1, dst1, agg1, cE1);
        count_k<<<(cE1 + 255) / 256, 256, 0, stream>>>(dst1, cnt1, cE1);
    }
    // ---- layer 1 GEMM: h = relu(mean1 @ w1l + b1 + x[:n1] @ w1r)
    {
        dim3 grid(cDH / 64, cN1 / 64);                // (4, 1280)
        sage_gemm_k<cDIN, true><<<grid, 256, 0, stream>>>(
            agg1, cnt1, x, w1l, w1r, b1, h, cDH);
    }
    // ---- layer 2 aggregate: agg2[dst2] += h[src2], cnt2[dst2] += 1
    {
        int total = cE2 * (cDH / 4);                  // 5,242,880 threads
        scatter_add_k<cDH><<<total / 256, 256, 0, stream>>>(h, src2, dst2, agg2, cE2);
        count_k<<<(cE2 + 255) / 256, 256, 0, stream>>>(dst2, cnt2, cE2);
    }
    // ---- layer 2 GEMM: out = mean2 @ w2l + b2 + h[:n2] @ w2r
    {
        dim3 grid(cDOUT / 64, cN2 / 64);              // (2, 128)
        sage_gemm_k<cDH, false><<<grid, 256, 0, stream>>>(
            agg2, cnt2, h, w2l, w2r, b2, out, cDOUT);
    }
}

// Round 2
// 519.721 us; speedup vs baseline: 3.6750x; 3.6750x over previous
//
#include <hip/hip_runtime.h>

// Problem constants (from reference)
constexpr int cN0 = 819200, cN1 = 81920, cN2 = 8192;
constexpr int cE1 = 819200, cE2 = 81920;
constexpr int cDIN = 128, cDH = 256, cDOUT = 128;

// ---------------------------------------------------------------------------
// CSR build: histogram -> exclusive scan -> permute (src sorted by dst).
// ---------------------------------------------------------------------------
__global__ __launch_bounds__(256) void hist_k(
    const int* __restrict__ dst, int* __restrict__ hist, int nedges)
{
    int e = blockIdx.x * 256 + threadIdx.x;
    if (e < nedges) atomicAdd(&hist[dst[e]], 1);
}

// Single-block in-place exclusive scan (shfl wave scan + LDS wave-sum scan).
__global__ __launch_bounds__(1024) void scan_k(int* __restrict__ a, int n)
{
    __shared__ int wsum[16];
    __shared__ int carry_s;
    const int tid = threadIdx.x;
    const int lane = tid & 63, wid = tid >> 6;
    if (tid == 0) carry_s = 0;
    __syncthreads();
    for (int base = 0; base < n; base += 1024) {
        int v = (base + tid < n) ? a[base + tid] : 0;
        int incl = v;
        #pragma unroll
        for (int off = 1; off < 64; off <<= 1) {
            int t = __shfl_up(incl, off, 64);
            if (lane >= off) incl += t;
        }
        if (lane == 63) wsum[wid] = incl;
        __syncthreads();                          // (A) wsum visible
        int wpre = 0;
        #pragma unroll
        for (int w = 0; w < 15; ++w) if (w < wid) wpre += wsum[w];
        int c = carry_s;
        if (base + tid < n) a[base + tid] = c + wpre + incl - v;  // exclusive
        __syncthreads();                          // (B) all reads of wsum/carry done
        if (tid == 1023) carry_s = c + wpre + incl;  // ordered by next iter's (A)
    }
}

// cursor starts as exclusive offsets; after this kernel cursor[d] = end(d).
__global__ __launch_bounds__(256) void build_k(
    const int* __restrict__ src, const int* __restrict__ dst,
    int* __restrict__ cursor, int* __restrict__ eidx, int nedges)
{
    int e = blockIdx.x * 256 + threadIdx.x;
    if (e < nedges) {
        int p = atomicAdd(&cursor[dst[e]], 1);
        eidx[p] = src[e];
    }
}

// ---------------------------------------------------------------------------
// Gather-mean: one wave per destination row. After build_k:
//   start(d) = (d==0) ? 0 : cursor[d-1],  end(d) = cursor[d].
// ---------------------------------------------------------------------------
template<int D>
__global__ __launch_bounds__(256) void agg_mean_k(
    const float* __restrict__ x, const int* __restrict__ cursor,
    const int* __restrict__ eidx, float* __restrict__ mean, int ndst)
{
    constexpr int VPL = D / 64;                  // floats per lane (2 or 4)
    const int row = blockIdx.x * 4 + (threadIdx.x >> 6);
    const int lane = threadIdx.x & 63;
    if (row >= ndst) return;
    const int start = (row == 0) ? 0 : cursor[row - 1];
    const int end = cursor[row];
    float acc[VPL] = {};
    for (int e = start; e < end; ++e) {
        const int s = eidx[e];
        const float* p = x + (size_t)s * D + lane * VPL;
        if (VPL == 2) {
            float2 v = *reinterpret_cast<const float2*>(p);
            acc[0] += v.x; acc[1] += v.y;
        } else {
            float4 v = *reinterpret_cast<const float4*>(p);
            acc[0] += v.x; acc[1] += v.y; acc[2] += v.z; acc[3] += v.w;
        }
    }
    const float inv = 1.0f / fmaxf((float)(end - start), 1.0f);
    float* o = mean + (size_t)row * D + lane * VPL;
    if (VPL == 2) {
        float2 v; v.x = acc[0] * inv; v.y = acc[1] * inv;
        *reinterpret_cast<float2*>(o) = v;
    } else {
        float4 v; v.x = acc[0] * inv; v.y = acc[1] * inv;
        v.z = acc[2] * inv; v.w = acc[3] * inv;
        *reinterpret_cast<float4*>(o) = v;
    }
}

// ---------------------------------------------------------------------------
// Fused SAGE GEMM:  out = act( mean @ W1 + xd @ W2 + bias )
//   mean, xd : [M][K1] row-major, W1,W2 : [K1][N] row-major.
// Tile 64x64, 256 threads, 4x4 micro-tile, BK=16, two K passes.
// ---------------------------------------------------------------------------
template<int K1, bool RELU>
__global__ __launch_bounds__(256) void sage_gemm_k(
    const float* __restrict__ meanA, const float* __restrict__ xd,
    const float* __restrict__ W1, const float* __restrict__ W2,
    const float* __restrict__ bias, float* __restrict__ out, int N)
{
    __shared__ float As[16][68];   // [k][row], padded
    __shared__ float Ws[16][64];   // [k][col]

    const int tid = threadIdx.x;
    const int row0 = blockIdx.y * 64;
    const int n0 = blockIdx.x * 64;

    const int lr = tid >> 2;          // 0..63  (A row within tile)
    const int lc = (tid & 3) * 4;     // 0,4,8,12
    const int wk = tid >> 4;          // 0..15
    const int wc = (tid & 15) * 4;    // 0..60
    const int tr = (tid >> 4) * 4;    // acc row base
    const int tc = (tid & 15) * 4;    // acc col base

    float acc[4][4] = {};

    for (int pass = 0; pass < 2; ++pass) {
        const float* __restrict__ A = pass ? xd : meanA;
        const float* __restrict__ W = pass ? W2 : W1;
        for (int k0 = 0; k0 < K1; k0 += 16) {
            float4 av = *reinterpret_cast<const float4*>(&A[(long)(row0 + lr) * K1 + k0 + lc]);
            float4 wv = *reinterpret_cast<const float4*>(&W[(long)(k0 + wk) * N + n0 + wc]);
            __syncthreads();
            As[lc + 0][lr] = av.x;
            As[lc + 1][lr] = av.y;
            As[lc + 2][lr] = av.z;
            As[lc + 3][lr] = av.w;
            *reinterpret_cast<float4*>(&Ws[wk][wc]) = wv;
            __syncthreads();
            #pragma unroll
            for (int kk = 0; kk < 16; ++kk) {
                float4 a = *reinterpret_cast<const float4*>(&As[kk][tr]);
                float4 b = *reinterpret_cast<const float4*>(&Ws[kk][tc]);
                acc[0][0] += a.x * b.x; acc[0][1] += a.x * b.y;
                acc[0][2] += a.x * b.z; acc[0][3] += a.x * b.w;
                acc[1][0] += a.y * b.x; acc[1][1] += a.y * b.y;
                acc[1][2] += a.y * b.z; acc[1][3] += a.y * b.w;
                acc[2][0] += a.z * b.x; acc[2][1] += a.z * b.y;
                acc[2][2] += a.z * b.z; acc[2][3] += a.z * b.w;
                acc[3][0] += a.w * b.x; acc[3][1] += a.w * b.y;
                acc[3][2] += a.w * b.z; acc[3][3] += a.w * b.w;
            }
        }
    }

    const float4 bv = *reinterpret_cast<const float4*>(&bias[n0 + tc]);
    #pragma unroll
    for (int i = 0; i < 4; ++i) {
        float4 o;
        o.x = acc[i][0] + bv.x;
        o.y = acc[i][1] + bv.y;
        o.z = acc[i][2] + bv.z;
        o.w = acc[i][3] + bv.w;
        if (RELU) {
            o.x = fmaxf(o.x, 0.0f); o.y = fmaxf(o.y, 0.0f);
            o.z = fmaxf(o.z, 0.0f); o.w = fmaxf(o.w, 0.0f);
        }
        *reinterpret_cast<float4*>(&out[(long)(row0 + tr + i) * N + n0 + tc]) = o;
    }
}

// ---------------------------------------------------------------------------
extern "C" void kernel_launch(void* const* d_in, const int* in_sizes, int n_in,
                              void* d_out, int out_size, void* d_ws, size_t ws_size,
                              hipStream_t stream)
{
    const float* x    = (const float*)d_in[0];
    const int*   src1 = (const int*)d_in[1];
    const int*   dst1 = (const int*)d_in[2];
    const int*   src2 = (const int*)d_in[3];
    const int*   dst2 = (const int*)d_in[4];
    const float* w1l  = (const float*)d_in[7];
    const float* b1   = (const float*)d_in[8];
    const float* w1r  = (const float*)d_in[9];
    const float* w2l  = (const float*)d_in[10];
    const float* b2   = (const float*)d_in[11];
    const float* w2r  = (const float*)d_in[12];
    float* out = (float*)d_out;

    // Workspace layout (total 134,578,176 B — same as the known-good R0 size):
    //   mean1 [N1*DIN] | h [N1*DH] | mean2 [N2*DH] | offs2 [N2] | eidx2 [E2]
    // Layer-1 CSR ints (offs1[N1], eidx1[E1] = 3.6 MB) ALIAS the mean2 region
    // (8.4 MB): they are dead before agg_mean_k<DH> writes mean2.
    float* mean1 = (float*)d_ws;
    float* h     = mean1 + (size_t)cN1 * cDIN;
    float* mean2 = h + (size_t)cN1 * cDH;
    int*   offs1 = (int*)mean2;                    // aliased (see above)
    int*   eidx1 = offs1 + cN1;
    int*   offs2 = (int*)(mean2 + (size_t)cN2 * cDH);
    int*   eidx2 = offs2 + cN2;

    // ---- layer 1: CSR build + gather-mean
    hipMemsetAsync(offs1, 0, (size_t)cN1 * sizeof(int), stream);
    hist_k<<<(cE1 + 255) / 256, 256, 0, stream>>>(dst1, offs1, cE1);
    scan_k<<<1, 1024, 0, stream>>>(offs1, cN1);
    build_k<<<(cE1 + 255) / 256, 256, 0, stream>>>(src1, dst1, offs1, eidx1, cE1);
    agg_mean_k<cDIN><<<cN1 / 4, 256, 0, stream>>>(x, offs1, eidx1, mean1, cN1);

    // ---- layer 1 GEMM: h = relu(mean1 @ w1l + b1 + x[:n1] @ w1r)
    {
        dim3 grid(cDH / 64, cN1 / 64);                // (4, 1280)
        sage_gemm_k<cDIN, true><<<grid, 256, 0, stream>>>(
            mean1, x, w1l, w1r, b1, h, cDH);
    }

    // ---- layer 2: CSR build + gather-mean (layer-1 CSR now dead; mean2 safe)
    hipMemsetAsync(offs2, 0, (size_t)cN2 * sizeof(int), stream);
    hist_k<<<(cE2 + 255) / 256, 256, 0, stream>>>(dst2, offs2, cE2);
    scan_k<<<1, 1024, 0, stream>>>(offs2, cN2);
    build_k<<<(cE2 + 255) / 256, 256, 0, stream>>>(src2, dst2, offs2, eidx2, cE2);
    agg_mean_k<cDH><<<cN2 / 4, 256, 0, stream>>>(h, offs2, eidx2, mean2, cN2);

    // ---- layer 2 GEMM: out = mean2 @ w2l + b2 + h[:n2] @ w2r
    {
        dim3 grid(cDOUT / 64, cN2 / 64);              // (2, 128)
        sage_gemm_k<cDH, false><<<grid, 256, 0, stream>>>(
            mean2, h, w2l, w2r, b2, out, cDOUT);
    }
}

// Round 3
// 280.722 us; speedup vs baseline: 6.8037x; 1.8514x over previous
//
#include <hip/hip_runtime.h>

// Problem constants
constexpr int cN0 = 819200, cN1 = 81920, cN2 = 8192;
constexpr int cE1 = 819200, cE2 = 81920;
constexpr int cDIN = 128, cDH = 256, cDOUT = 128;

typedef __attribute__((ext_vector_type(8))) short bf16x8;
typedef __attribute__((ext_vector_type(4))) float f32x4;
typedef __attribute__((ext_vector_type(8))) unsigned short u16x8;

__device__ __forceinline__ unsigned short f2bf(float f) {
    unsigned u = __builtin_bit_cast(unsigned, f);
    u += 0x7FFF + ((u >> 16) & 1);            // round-to-nearest-even
    return (unsigned short)(u >> 16);
}
__device__ __forceinline__ float bf2f(unsigned short s) {
    unsigned u = ((unsigned)s) << 16;
    return __builtin_bit_cast(float, u);
}

// ---------------------------------------------------------------------------
// CSR build: histogram -> scan -> permute
// ---------------------------------------------------------------------------
__global__ __launch_bounds__(256) void hist_k(
    const int* __restrict__ dst, int* __restrict__ hist, int nedges)
{
    int e = blockIdx.x * 256 + threadIdx.x;
    if (e < nedges) atomicAdd(&hist[dst[e]], 1);
}

// hierarchical scan for n = 80*1024 = 81920
__global__ __launch_bounds__(1024) void partial_k(
    const int* __restrict__ a, int* __restrict__ part)
{
    const int tid = threadIdx.x, lane = tid & 63, wid = tid >> 6;
    int v = a[blockIdx.x * 1024 + tid];
    #pragma unroll
    for (int off = 32; off; off >>= 1) v += __shfl_xor(v, off);
    __shared__ int ws[16];
    if (lane == 0) ws[wid] = v;
    __syncthreads();
    if (tid == 0) {
        int s = 0;
        #pragma unroll
        for (int i = 0; i < 16; ++i) s += ws[i];
        part[blockIdx.x] = s;
    }
}

__global__ __launch_bounds__(128) void scanp_k(int* __restrict__ part) // n=80
{
    const int tid = threadIdx.x, lane = tid & 63, wid = tid >> 6;
    int v = (tid < 80) ? part[tid] : 0;
    int incl = v;
    #pragma unroll
    for (int off = 1; off < 64; off <<= 1) {
        int t = __shfl_up(incl, off, 64);
        if (lane >= off) incl += t;
    }
    __shared__ int w0;
    if (wid == 0 && lane == 63) w0 = incl;
    __syncthreads();
    int pre = wid ? w0 : 0;
    if (tid < 80) part[tid] = pre + incl - v;   // exclusive
}

__global__ __launch_bounds__(1024) void final_k(
    int* __restrict__ a, const int* __restrict__ part)
{
    const int tid = threadIdx.x, lane = tid & 63, wid = tid >> 6;
    const int g = blockIdx.x * 1024 + tid;
    int v = a[g];
    int incl = v;
    #pragma unroll
    for (int off = 1; off < 64; off <<= 1) {
        int t = __shfl_up(incl, off, 64);
        if (lane >= off) incl += t;
    }
    __shared__ int ws[16];
    if (lane == 63) ws[wid] = incl;
    __syncthreads();
    int pre = 0;
    #pragma unroll
    for (int i = 0; i < 16; ++i) if (i < wid) pre += ws[i];
    a[g] = part[blockIdx.x] + pre + incl - v;   // exclusive
}

// single-block scan (layer 2, n=8192 -> 8 iters)
__global__ __launch_bounds__(1024) void scan_k(int* __restrict__ a, int n)
{
    __shared__ int wsum[16];
    __shared__ int carry_s;
    const int tid = threadIdx.x;
    const int lane = tid & 63, wid = tid >> 6;
    if (tid == 0) carry_s = 0;
    __syncthreads();
    for (int base = 0; base < n; base += 1024) {
        int v = (base + tid < n) ? a[base + tid] : 0;
        int incl = v;
        #pragma unroll
        for (int off = 1; off < 64; off <<= 1) {
            int t = __shfl_up(incl, off, 64);
            if (lane >= off) incl += t;
        }
        if (lane == 63) wsum[wid] = incl;
        __syncthreads();
        int wpre = 0;
        #pragma unroll
        for (int w = 0; w < 15; ++w) if (w < wid) wpre += wsum[w];
        int c = carry_s;
        if (base + tid < n) a[base + tid] = c + wpre + incl - v;
        __syncthreads();
        if (tid == 1023) carry_s = c + wpre + incl;
    }
}

__global__ __launch_bounds__(256) void build_k(
    const int* __restrict__ src, const int* __restrict__ dst,
    int* __restrict__ cursor, int* __restrict__ eidx, int nedges)
{
    int e = blockIdx.x * 256 + threadIdx.x;
    if (e < nedges) {
        int p = atomicAdd(&cursor[dst[e]], 1);
        eidx[p] = src[e];
    }
}

// ---------------------------------------------------------------------------
// Layer-1 aggregate: one wave per dst row; half-wave per edge (2 in flight).
// Writes mean (bf16) into A1[row][0:128] and converts x[row] into A1[row][128:256].
// ---------------------------------------------------------------------------
__global__ __launch_bounds__(256) void agg1_k(
    const float* __restrict__ x, const int* __restrict__ cursor,
    const int* __restrict__ eidx, unsigned short* __restrict__ A1)
{
    const int row = blockIdx.x * 4 + (threadIdx.x >> 6);
    const int lane = threadIdx.x & 63;
    const int half = lane >> 5, li = lane & 31;
    const int start = row ? cursor[row - 1] : 0;
    const int end = cursor[row];
    float ax = 0.f, ay = 0.f, az = 0.f, aw = 0.f;
    for (int e = start + half; e < end; e += 2) {
        const int s = eidx[e];
        float4 v = *reinterpret_cast<const float4*>(x + (size_t)s * cDIN + li * 4);
        ax += v.x; ay += v.y; az += v.z; aw += v.w;
    }
    ax += __shfl_xor(ax, 32);
    ay += __shfl_xor(ay, 32);
    az += __shfl_xor(az, 32);
    aw += __shfl_xor(aw, 32);
    const float inv = 1.0f / fmaxf((float)(end - start), 1.0f);
    if (half == 0) {
        ushort4 o;
        o.x = f2bf(ax * inv); o.y = f2bf(ay * inv);
        o.z = f2bf(az * inv); o.w = f2bf(aw * inv);
        *reinterpret_cast<ushort4*>(A1 + (size_t)row * 256 + li * 4) = o;
    }
    // convert x[row] -> A1 right half (x_dst operand)
    float2 xv = *reinterpret_cast<const float2*>(x + (size_t)row * cDIN + lane * 2);
    unsigned pk = (unsigned)f2bf(xv.x) | ((unsigned)f2bf(xv.y) << 16);
    *reinterpret_cast<unsigned*>(A1 + (size_t)row * 256 + 128 + lane * 2) = pk;
}

// ---------------------------------------------------------------------------
// Layer-2 aggregate: gather bf16 h rows, mean into A2[row][0:256] (bf16).
// ---------------------------------------------------------------------------
__global__ __launch_bounds__(256) void agg2_k(
    const unsigned short* __restrict__ h, const int* __restrict__ cursor,
    const int* __restrict__ eidx, unsigned short* __restrict__ A2)
{
    const int row = blockIdx.x * 4 + (threadIdx.x >> 6);
    const int lane = threadIdx.x & 63;
    const int half = lane >> 5, li = lane & 31;
    const int start = row ? cursor[row - 1] : 0;
    const int end = cursor[row];
    float acc[8] = {};
    for (int e = start + half; e < end; e += 2) {
        const int s = eidx[e];
        u16x8 v = *reinterpret_cast<const u16x8*>(h + (size_t)s * cDH + li * 8);
        #pragma unroll
        for (int i = 0; i < 8; ++i) acc[i] += bf2f(v[i]);
    }
    #pragma unroll
    for (int i = 0; i < 8; ++i) acc[i] += __shfl_xor(acc[i], 32);
    const float inv = 1.0f / fmaxf((float)(end - start), 1.0f);
    if (half == 0) {
        u16x8 o;
        #pragma unroll
        for (int i = 0; i < 8; ++i) o[i] = f2bf(acc[i] * inv);
        *reinterpret_cast<u16x8*>(A2 + (size_t)row * 512 + li * 8) = o;
    }
}

// ---------------------------------------------------------------------------
// Weight prep: W1c[n][k] = concat(w1l,w1r)^T, W2c[n][k] = concat(w2l,w2r)^T (bf16)
// ---------------------------------------------------------------------------
__global__ __launch_bounds__(256) void wprep_k(
    const float* __restrict__ w1l, const float* __restrict__ w1r,
    const float* __restrict__ w2l, const float* __restrict__ w2r,
    unsigned short* __restrict__ W1c, unsigned short* __restrict__ W2c)
{
    int id = blockIdx.x * 256 + threadIdx.x;
    if (id < 256 * 256) {
        int n = id >> 8, k = id & 255;
        float v = (k < 128) ? w1l[k * 256 + n] : w1r[(k - 128) * 256 + n];
        W1c[n * 256 + k] = f2bf(v);
    } else {
        int id2 = id - 256 * 256;
        int n = id2 >> 9, k = id2 & 511;
        float v = (k < 256) ? w2l[k * 128 + n] : w2r[(k - 256) * 128 + n];
        W2c[n * 512 + k] = f2bf(v);
    }
}

// ---------------------------------------------------------------------------
// bf16 MFMA GEMM: C[M][N] = A[M][K] @ Bt[N][K]^T + bias, tile 128x128, 4 waves.
// L1MODE: relu, store bf16 h, duplicate rows<8192 into A2 right half.
// else:   store f32 out.
// ---------------------------------------------------------------------------
template<int K, int N, bool L1MODE>
__global__ __launch_bounds__(256) void mfma_gemm_k(
    const unsigned short* __restrict__ A, const unsigned short* __restrict__ Bt,
    const float* __restrict__ bias,
    unsigned short* __restrict__ hout, unsigned short* __restrict__ a2r,
    float* __restrict__ fout)
{
    constexpr int LD = 40;                     // LDS row stride (bf16), 80 B
    __shared__ unsigned short As[128 * LD];
    __shared__ unsigned short Bs[128 * LD];

    const int tid = threadIdx.x;
    const int l = tid & 63, w = tid >> 6;
    const int q = l >> 4, r16 = l & 15;
    const int wr0 = (w >> 1) * 64, wc0 = (w & 1) * 64;
    const int n0 = blockIdx.x * 128, row0 = blockIdx.y * 128;

    const f32x4 zero = {0.f, 0.f, 0.f, 0.f};
    f32x4 acc[4][4];
    #pragma unroll
    for (int m = 0; m < 4; ++m)
        #pragma unroll
        for (int n = 0; n < 4; ++n) acc[m][n] = zero;

    for (int k0 = 0; k0 < K; k0 += 32) {
        __syncthreads();                       // prev iter's reads complete
        #pragma unroll
        for (int c = 0; c < 2; ++c) {
            int z = tid + c * 256;             // 16B slot 0..511
            int r = z >> 2, o16 = z & 3;
            bf16x8 av = *reinterpret_cast<const bf16x8*>(A + (size_t)(row0 + r) * K + k0 + o16 * 8);
            bf16x8 bv = *reinterpret_cast<const bf16x8*>(Bt + (size_t)(n0 + r) * K + k0 + o16 * 8);
            *reinterpret_cast<bf16x8*>(As + r * LD + o16 * 8) = av;
            *reinterpret_cast<bf16x8*>(Bs + r * LD + o16 * 8) = bv;
        }
        __syncthreads();                       // LDS visible
        bf16x8 af[4], bg[4];
        #pragma unroll
        for (int m = 0; m < 4; ++m)
            af[m] = *reinterpret_cast<const bf16x8*>(As + (wr0 + 16 * m + r16) * LD + q * 8);
        #pragma unroll
        for (int n = 0; n < 4; ++n)
            bg[n] = *reinterpret_cast<const bf16x8*>(Bs + (wc0 + 16 * n + r16) * LD + q * 8);
        #pragma unroll
        for (int m = 0; m < 4; ++m)
            #pragma unroll
            for (int n = 0; n < 4; ++n)
                acc[m][n] = __builtin_amdgcn_mfma_f32_16x16x32_bf16(af[m], bg[n], acc[m][n], 0, 0, 0);
    }

    // epilogue — D layout: col = lane&15, row = 4*(lane>>4) + reg  [m89-verified]
    #pragma unroll
    for (int n = 0; n < 4; ++n) {
        const int col = n0 + wc0 + 16 * n + r16;
        const float bv = bias[col];
        #pragma unroll
        for (int m = 0; m < 4; ++m) {
            #pragma unroll
            for (int j = 0; j < 4; ++j) {
                const int row = row0 + wr0 + 16 * m + 4 * q + j;
                float v = acc[m][n][j] + bv;
                if (L1MODE) {
                    v = fmaxf(v, 0.f);
                    unsigned short b = f2bf(v);
                    hout[(size_t)row * N + col] = b;
                    if (row < cN2) a2r[(size_t)row * 512 + col] = b;
                } else {
                    fout[(size_t)row * N + col] = v;
                }
            }
        }
    }
}

// ---------------------------------------------------------------------------
extern "C" void kernel_launch(void* const* d_in, const int* in_sizes, int n_in,
                              void* d_out, int out_size, void* d_ws, size_t ws_size,
                              hipStream_t stream)
{
    const float* x    = (const float*)d_in[0];
    const int*   src1 = (const int*)d_in[1];
    const int*   dst1 = (const int*)d_in[2];
    const int*   src2 = (const int*)d_in[3];
    const int*   dst2 = (const int*)d_in[4];
    const float* w1l  = (const float*)d_in[7];
    const float* b1   = (const float*)d_in[8];
    const float* w1r  = (const float*)d_in[9];
    const float* w2l  = (const float*)d_in[10];
    const float* b2   = (const float*)d_in[11];
    const float* w2r  = (const float*)d_in[12];
    float* out = (float*)d_out;

    // Workspace layout (bf16 operands), ~96.5 MB total:
    unsigned short* A1  = (unsigned short*)d_ws;        // [81920][256]
    unsigned short* h   = A1 + (size_t)cN1 * 256;       // [81920][256]
    unsigned short* A2  = h + (size_t)cN1 * 256;        // [8192][512]
    unsigned short* W1c = A2 + (size_t)cN2 * 512;       // [256][256]
    unsigned short* W2c = W1c + 256 * 256;              // [128][512]
    int* offs1 = (int*)(W2c + 128 * 512);
    int* eidx1 = offs1 + cN1;
    int* offs2 = eidx1 + cE1;
    int* eidx2 = offs2 + cN2;
    int* part1 = eidx2 + cE2;                           // 80 ints

    hipMemsetAsync(offs1, 0, (size_t)cN1 * sizeof(int), stream);
    hipMemsetAsync(offs2, 0, (size_t)cN2 * sizeof(int), stream);

    wprep_k<<<(256 * 256 + 128 * 512) / 256, 256, 0, stream>>>(w1l, w1r, w2l, w2r, W1c, W2c);

    // ---- layer 1 CSR + aggregate
    hist_k<<<cE1 / 256, 256, 0, stream>>>(dst1, offs1, cE1);
    partial_k<<<cN1 / 1024, 1024, 0, stream>>>(offs1, part1);
    scanp_k<<<1, 128, 0, stream>>>(part1);
    final_k<<<cN1 / 1024, 1024, 0, stream>>>(offs1, part1);
    build_k<<<cE1 / 256, 256, 0, stream>>>(src1, dst1, offs1, eidx1, cE1);
    agg1_k<<<cN1 / 4, 256, 0, stream>>>(x, offs1, eidx1, A1);

    // ---- layer 1 GEMM: h = relu(A1 @ W1c^T + b1), + A2 right-half copy
    mfma_gemm_k<256, 256, true><<<dim3(2, cN1 / 128), 256, 0, stream>>>(
        A1, W1c, b1, h, A2 + 256, nullptr);

    // ---- layer 2 CSR + aggregate
    hist_k<<<cE2 / 256, 256, 0, stream>>>(dst2, offs2, cE2);
    scan_k<<<1, 1024, 0, stream>>>(offs2, cN2);
    build_k<<<cE2 / 256, 256, 0, stream>>>(src2, dst2, offs2, eidx2, cE2);
    agg2_k<<<cN2 / 4, 256, 0, stream>>>(h, offs2, eidx2, A2);

    // ---- layer 2 GEMM: out = A2 @ W2c^T + b2
    mfma_gemm_k<512, 128, false><<<dim3(1, cN2 / 128), 256, 0, stream>>>(
        A2, W2c, b2, nullptr, nullptr, out);
}

// Round 4
// 240.334 us; speedup vs baseline: 7.9471x; 1.1681x over previous
//
#include <hip/hip_runtime.h>

// Problem constants
constexpr int cN0 = 819200, cN1 = 81920, cN2 = 8192;
constexpr int cE1 = 819200, cE2 = 81920;
constexpr int cDIN = 128, cDH = 256, cDOUT = 128;
constexpr int cNOFF = cN1 + cN2;               // 90112 = 88 * 1024

typedef __attribute__((ext_vector_type(8))) short bf16x8;
typedef __attribute__((ext_vector_type(4))) float f32x4;
typedef __attribute__((ext_vector_type(8))) unsigned short u16x8;

__device__ __forceinline__ unsigned short f2bf(float f) {
    unsigned u = __builtin_bit_cast(unsigned, f);
    u += 0x7FFF + ((u >> 16) & 1);            // RNE
    return (unsigned short)(u >> 16);
}
__device__ __forceinline__ float bf2f(unsigned short s) {
    unsigned u = ((unsigned)s) << 16;
    return __builtin_bit_cast(float, u);
}

// ---------------------------------------------------------------------------
// setup: zero offs[90112] + convert both weight matrices to bf16 W^T concat.
// ---------------------------------------------------------------------------
__global__ __launch_bounds__(256) void setup_k(
    int* __restrict__ offs,
    const float* __restrict__ w1l, const float* __restrict__ w1r,
    const float* __restrict__ w2l, const float* __restrict__ w2r,
    unsigned short* __restrict__ W1c, unsigned short* __restrict__ W2c)
{
    int id = blockIdx.x * 256 + threadIdx.x;
    if (id < cNOFF) { offs[id] = 0; return; }
    int t = id - cNOFF;
    if (t < 256 * 256) {
        int n = t >> 8, k = t & 255;
        float v = (k < 128) ? w1l[k * 256 + n] : w1r[(k - 128) * 256 + n];
        W1c[n * 256 + k] = f2bf(v);
    } else {
        t -= 256 * 256;
        if (t < 128 * 512) {
            int n = t >> 9, k = t & 511;
            float v = (k < 256) ? w2l[k * 128 + n] : w2r[(k - 256) * 128 + n];
            W2c[n * 512 + k] = f2bf(v);
        }
    }
}

// ---------------------------------------------------------------------------
// fused histogram over both edge lists
// ---------------------------------------------------------------------------
__global__ __launch_bounds__(256) void hist_k(
    const int* __restrict__ dst1, const int* __restrict__ dst2,
    int* __restrict__ offs)
{
    int e = blockIdx.x * 256 + threadIdx.x;
    if (e < cE1) atomicAdd(&offs[dst1[e]], 1);
    else {
        int e2 = e - cE1;
        if (e2 < cE2) atomicAdd(&offs[cN1 + dst2[e2]], 1);
    }
}

// ---------------------------------------------------------------------------
// hierarchical exclusive scan over offs[90112] (88 blocks of 1024)
// ---------------------------------------------------------------------------
__global__ __launch_bounds__(1024) void partial_k(
    const int* __restrict__ a, int* __restrict__ part)
{
    const int tid = threadIdx.x, lane = tid & 63, wid = tid >> 6;
    int v = a[blockIdx.x * 1024 + tid];
    #pragma unroll
    for (int off = 32; off; off >>= 1) v += __shfl_xor(v, off);
    __shared__ int ws[16];
    if (lane == 0) ws[wid] = v;
    __syncthreads();
    if (tid == 0) {
        int s = 0;
        #pragma unroll
        for (int i = 0; i < 16; ++i) s += ws[i];
        part[blockIdx.x] = s;
    }
}

__global__ __launch_bounds__(128) void scanp_k(int* __restrict__ part) // n=88
{
    const int tid = threadIdx.x, lane = tid & 63, wid = tid >> 6;
    int v = (tid < 88) ? part[tid] : 0;
    int incl = v;
    #pragma unroll
    for (int off = 1; off < 64; off <<= 1) {
        int t = __shfl_up(incl, off, 64);
        if (lane >= off) incl += t;
    }
    __shared__ int w0;
    if (wid == 0 && lane == 63) w0 = incl;
    __syncthreads();
    int pre = wid ? w0 : 0;
    if (tid < 88) part[tid] = pre + incl - v;   // exclusive
}

__global__ __launch_bounds__(1024) void final_k(
    int* __restrict__ a, const int* __restrict__ part)
{
    const int tid = threadIdx.x, lane = tid & 63, wid = tid >> 6;
    const int g = blockIdx.x * 1024 + tid;
    int v = a[g];
    int incl = v;
    #pragma unroll
    for (int off = 1; off < 64; off <<= 1) {
        int t = __shfl_up(incl, off, 64);
        if (lane >= off) incl += t;
    }
    __shared__ int ws[16];
    if (lane == 63) ws[wid] = incl;
    __syncthreads();
    int pre = 0;
    #pragma unroll
    for (int i = 0; i < 16; ++i) if (i < wid) pre += ws[i];
    int r = part[blockIdx.x] + pre + incl - v;          // global exclusive
    if (g >= cN1) r -= cE1;                              // layer-2 local
    a[g] = r;
}

// ---------------------------------------------------------------------------
// fused CSR permute for both layers (cursor -> end offsets afterwards)
// ---------------------------------------------------------------------------
__global__ __launch_bounds__(256) void build_k(
    const int* __restrict__ src1, const int* __restrict__ dst1,
    const int* __restrict__ src2, const int* __restrict__ dst2,
    int* __restrict__ offs, int* __restrict__ eidx1, int* __restrict__ eidx2)
{
    int e = blockIdx.x * 256 + threadIdx.x;
    if (e < cE1) {
        int p = atomicAdd(&offs[dst1[e]], 1);
        eidx1[p] = src1[e];
    } else {
        int e2 = e - cE1;
        if (e2 < cE2) {
            int p = atomicAdd(&offs[cN1 + dst2[e2]], 1);
            eidx2[p] = src2[e2];
        }
    }
}

// ---------------------------------------------------------------------------
// Layer-1 aggregate: one wave per dst row, 16-lane group per edge (4 in flight).
// mean1[row][0:128] bf16.
// ---------------------------------------------------------------------------
__global__ __launch_bounds__(256) void agg1_k(
    const float* __restrict__ x, const int* __restrict__ cursor,
    const int* __restrict__ eidx, unsigned short* __restrict__ mean1)
{
    const int row = blockIdx.x * 4 + (threadIdx.x >> 6);
    const int lane = threadIdx.x & 63;
    const int g = lane >> 4, li = lane & 15;
    const int start = row ? cursor[row - 1] : 0;
    const int end = cursor[row];
    float acc[8] = {};
    for (int e = start + g; e < end; e += 4) {
        const int s = eidx[e];
        const float4* p = reinterpret_cast<const float4*>(x + (size_t)s * cDIN + li * 8);
        float4 a = p[0], b = p[1];
        acc[0] += a.x; acc[1] += a.y; acc[2] += a.z; acc[3] += a.w;
        acc[4] += b.x; acc[5] += b.y; acc[6] += b.z; acc[7] += b.w;
    }
    #pragma unroll
    for (int i = 0; i < 8; ++i) {
        acc[i] += __shfl_xor(acc[i], 16);
        acc[i] += __shfl_xor(acc[i], 32);
    }
    if (g == 0) {
        const float inv = 1.0f / fmaxf((float)(end - start), 1.0f);
        u16x8 o;
        #pragma unroll
        for (int i = 0; i < 8; ++i) o[i] = f2bf(acc[i] * inv);
        *reinterpret_cast<u16x8*>(mean1 + (size_t)row * cDIN + li * 8) = o;
    }
}

// ---------------------------------------------------------------------------
// Layer-2 aggregate: gather bf16 h rows; mean2[row][0:256] bf16.
// ---------------------------------------------------------------------------
__global__ __launch_bounds__(256) void agg2_k(
    const unsigned short* __restrict__ h, const int* __restrict__ cursor,
    const int* __restrict__ eidx, unsigned short* __restrict__ mean2)
{
    const int row = blockIdx.x * 4 + (threadIdx.x >> 6);
    const int lane = threadIdx.x & 63;
    const int g = lane >> 4, li = lane & 15;
    const int start = row ? cursor[row - 1] : 0;
    const int end = cursor[row];
    float acc[16] = {};
    for (int e = start + g; e < end; e += 4) {
        const int s = eidx[e];
        const u16x8* p = reinterpret_cast<const u16x8*>(h + (size_t)s * cDH + li * 16);
        u16x8 a = p[0], b = p[1];
        #pragma unroll
        for (int i = 0; i < 8; ++i) { acc[i] += bf2f(a[i]); acc[8 + i] += bf2f(b[i]); }
    }
    #pragma unroll
    for (int i = 0; i < 16; ++i) {
        acc[i] += __shfl_xor(acc[i], 16);
        acc[i] += __shfl_xor(acc[i], 32);
    }
    if (g == 0) {
        const float inv = 1.0f / fmaxf((float)(end - start), 1.0f);
        u16x8 o0, o1;
        #pragma unroll
        for (int i = 0; i < 8; ++i) { o0[i] = f2bf(acc[i] * inv); o1[i] = f2bf(acc[8 + i] * inv); }
        u16x8* q = reinterpret_cast<u16x8*>(mean2 + (size_t)row * cDH + li * 16);
        q[0] = o0; q[1] = o1;
    }
}

// ---------------------------------------------------------------------------
// bf16 MFMA GEMM, A = [Aleft | Aright] split at KL = K/2.
//   Aleft: bf16 [M][KL].  Aright: RIGHT_F32 ? f32 [M][KL] (cvt in loader)
//                                           : bf16 [M][KL].
//   Bt: bf16 [N][K] (pre-transposed, concatenated).
// TM=128: 4 waves 2x2 (64x64 each).  TM=64: 4 waves 1x4 (64x32 each).
// L1MODE: relu + bf16 store to hout. else f32 store to fout.
// ---------------------------------------------------------------------------
template<int K, int N, int TM, bool RIGHT_F32, bool L1MODE>
__global__ __launch_bounds__(256) void mfma_gemm_k(
    const unsigned short* __restrict__ Aleft, const void* __restrict__ Aright,
    const unsigned short* __restrict__ Bt, const float* __restrict__ bias,
    unsigned short* __restrict__ hout, float* __restrict__ fout)
{
    constexpr int KL = K / 2;
    constexpr int LD = 40;
    constexpr int WR = 4;                       // 16-row frags per wave
    constexpr int WC = (TM == 128) ? 4 : 2;     // 16-col frags per wave
    __shared__ unsigned short As[TM * LD];
    __shared__ unsigned short Bs[128 * LD];

    const int tid = threadIdx.x;
    const int l = tid & 63, w = tid >> 6;
    const int q = l >> 4, r16 = l & 15;
    const int wr0 = (TM == 128) ? (w >> 1) * 64 : 0;
    const int wc0 = (TM == 128) ? (w & 1) * 64 : w * 32;
    const int n0 = blockIdx.x * 128, row0 = blockIdx.y * TM;

    const f32x4 zero = {0.f, 0.f, 0.f, 0.f};
    f32x4 acc[WR][WC];
    #pragma unroll
    for (int m = 0; m < WR; ++m)
        #pragma unroll
        for (int n = 0; n < WC; ++n) acc[m][n] = zero;

    for (int k0 = 0; k0 < K; k0 += 32) {
        const bool left = (k0 < KL);
        __syncthreads();
        // A tile: TM*4 16B slots
        #pragma unroll
        for (int c = 0; c < (TM * 4) / 256; ++c) {
            int z = tid + c * 256;
            int r = z >> 2, o16 = z & 3;
            bf16x8 av;
            if (left) {
                av = *reinterpret_cast<const bf16x8*>(Aleft + (size_t)(row0 + r) * KL + k0 + o16 * 8);
            } else if (RIGHT_F32) {
                const float* p = (const float*)Aright + (size_t)(row0 + r) * KL + (k0 - KL) + o16 * 8;
                float4 u = *reinterpret_cast<const float4*>(p);
                float4 v = *reinterpret_cast<const float4*>(p + 4);
                av[0] = (short)f2bf(u.x); av[1] = (short)f2bf(u.y);
                av[2] = (short)f2bf(u.z); av[3] = (short)f2bf(u.w);
                av[4] = (short)f2bf(v.x); av[5] = (short)f2bf(v.y);
                av[6] = (short)f2bf(v.z); av[7] = (short)f2bf(v.w);
            } else {
                av = *reinterpret_cast<const bf16x8*>((const unsigned short*)Aright + (size_t)(row0 + r) * KL + (k0 - KL) + o16 * 8);
            }
            *reinterpret_cast<bf16x8*>(As + r * LD + o16 * 8) = av;
        }
        // B tile: 512 slots
        #pragma unroll
        for (int c = 0; c < 2; ++c) {
            int z = tid + c * 256;
            int r = z >> 2, o16 = z & 3;
            bf16x8 bv = *reinterpret_cast<const bf16x8*>(Bt + (size_t)(n0 + r) * K + k0 + o16 * 8);
            *reinterpret_cast<bf16x8*>(Bs + r * LD + o16 * 8) = bv;
        }
        __syncthreads();
        bf16x8 af[WR], bg[WC];
        #pragma unroll
        for (int m = 0; m < WR; ++m)
            af[m] = *reinterpret_cast<const bf16x8*>(As + (wr0 + 16 * m + r16) * LD + q * 8);
        #pragma unroll
        for (int n = 0; n < WC; ++n)
            bg[n] = *reinterpret_cast<const bf16x8*>(Bs + (wc0 + 16 * n + r16) * LD + q * 8);
        #pragma unroll
        for (int m = 0; m < WR; ++m)
            #pragma unroll
            for (int n = 0; n < WC; ++n)
                acc[m][n] = __builtin_amdgcn_mfma_f32_16x16x32_bf16(af[m], bg[n], acc[m][n], 0, 0, 0);
    }

    // epilogue — D layout: col = lane&15, row = 4*(lane>>4) + reg
    #pragma unroll
    for (int n = 0; n < WC; ++n) {
        const int col = n0 + wc0 + 16 * n + r16;
        const float bv = bias[col];
        #pragma unroll
        for (int m = 0; m < WR; ++m) {
            #pragma unroll
            for (int j = 0; j < 4; ++j) {
                const int row = row0 + wr0 + 16 * m + 4 * q + j;
                float v = acc[m][n][j] + bv;
                if (L1MODE) {
                    hout[(size_t)row * N + col] = f2bf(fmaxf(v, 0.f));
                } else {
                    fout[(size_t)row * N + col] = v;
                }
            }
        }
    }
}

// ---------------------------------------------------------------------------
extern "C" void kernel_launch(void* const* d_in, const int* in_sizes, int n_in,
                              void* d_out, int out_size, void* d_ws, size_t ws_size,
                              hipStream_t stream)
{
    const float* x    = (const float*)d_in[0];
    const int*   src1 = (const int*)d_in[1];
    const int*   dst1 = (const int*)d_in[2];
    const int*   src2 = (const int*)d_in[3];
    const int*   dst2 = (const int*)d_in[4];
    const float* w1l  = (const float*)d_in[7];
    const float* b1   = (const float*)d_in[8];
    const float* w1r  = (const float*)d_in[9];
    const float* w2l  = (const float*)d_in[10];
    const float* b2   = (const float*)d_in[11];
    const float* w2r  = (const float*)d_in[12];
    float* out = (float*)d_out;

    // Workspace (~71 MB):
    unsigned short* mean1 = (unsigned short*)d_ws;        // [81920][128] bf16
    unsigned short* h     = mean1 + (size_t)cN1 * cDIN;   // [81920][256] bf16
    unsigned short* mean2 = h + (size_t)cN1 * cDH;        // [8192][256] bf16
    unsigned short* W1c   = mean2 + (size_t)cN2 * cDH;    // [256][256]
    unsigned short* W2c   = W1c + 256 * 256;              // [128][512]
    int* offs  = (int*)(W2c + 128 * 512);                 // [90112] (offs1|offs2)
    int* eidx1 = offs + cNOFF;                            // [819200]
    int* eidx2 = eidx1 + cE1;                             // [81920]
    int* part  = eidx2 + cE2;                             // [88]

    // 1. setup: zero offs + weight conversion
    {
        int total = cNOFF + 256 * 256 + 128 * 512;        // 221184
        setup_k<<<(total + 255) / 256, 256, 0, stream>>>(offs, w1l, w1r, w2l, w2r, W1c, W2c);
    }
    // 2-6. CSR for both layers
    hist_k<<<(cE1 + cE2) / 256, 256, 0, stream>>>(dst1, dst2, offs);
    partial_k<<<cNOFF / 1024, 1024, 0, stream>>>(offs, part);
    scanp_k<<<1, 128, 0, stream>>>(part);
    final_k<<<cNOFF / 1024, 1024, 0, stream>>>(offs, part);
    build_k<<<(cE1 + cE2) / 256, 256, 0, stream>>>(src1, dst1, src2, dst2, offs, eidx1, eidx2);

    // 7. layer-1 aggregate
    agg1_k<<<cN1 / 4, 256, 0, stream>>>(x, offs, eidx1, mean1);

    // 8. layer-1 GEMM: h = relu([mean1 | x[:n1]] @ W1c^T + b1)
    mfma_gemm_k<256, 256, 128, true, true><<<dim3(2, cN1 / 128), 256, 0, stream>>>(
        mean1, (const void*)x, W1c, b1, h, nullptr);

    // 9. layer-2 aggregate
    agg2_k<<<cN2 / 4, 256, 0, stream>>>(h, offs + cN1, eidx2, mean2);

    // 10. layer-2 GEMM: out = [mean2 | h[:n2]] @ W2c^T + b2
    mfma_gemm_k<512, 128, 64, false, false><<<dim3(1, cN2 / 64), 256, 0, stream>>>(
        mean2, (const void*)h, W2c, b2, nullptr, out);
}